// Round 3
// baseline (271.591 us; speedup 1.0000x reference)
//
#include <hip/hip_runtime.h>
#include <hip/hip_bf16.h>
#include <math.h>

typedef __attribute__((ext_vector_type(8))) short short8;
typedef __attribute__((ext_vector_type(4))) float f32x4;

#define NJ 24

// ---- ws image: per-fragment 1KB blocks (64 lanes x 16B), lane-major ----
// GEMM1: per joint 15 blocks (nt=0..4, s=0..2)   lane(rm,g) holds W1T[n=nt*16+rm][k'=s*32+g*8 ..+7]
// GEMM2: per joint 12 blocks (nt=0..3, s=0..2)   W2T[n][k]
// Wp   : 36 blocks (nt=0..3, s=0..8)             WpT[n][k]
#define F1_J   7680                     // 15*512 shorts
#define F2_OFF (NJ*F1_J)                // 184320
#define F2_J   6144                     // 12*512
#define FP_OFF (F2_OFF + NJ*F2_J)       // 331776
#define IMG_SHORTS (FP_OFF + 36*512)    // 350208 shorts = 700416 B

#define MFMA(A,B,C) __builtin_amdgcn_mfma_f32_16x16x32_bf16((A),(B),(C),0,0,0)
#define BAR() do { asm volatile("s_waitcnt lgkmcnt(0)" ::: "memory"); \
                   __builtin_amdgcn_s_barrier(); \
                   asm volatile("" ::: "memory"); } while(0)

__device__ __forceinline__ short f2bf(float f) {      // prep only
  union { float f; unsigned u; } v; v.f = f;
  unsigned r = v.u + 0x7FFFu + ((v.u >> 16) & 1u);    // RNE
  return (short)(r >> 16);
}
__device__ __forceinline__ short sbf(float f) {
  __hip_bfloat16 h = __float2bfloat16(f);
  return *reinterpret_cast<short*>(&h);
}

__global__ __launch_bounds__(256) void prep_kernel(
    const float* __restrict__ W1, const float* __restrict__ W2,
    const float* __restrict__ Wp, short* __restrict__ img) {
  int t = blockIdx.x * 256 + threadIdx.x;
  if (t >= IMG_SHORTS) return;
  float v = 0.f;
  if (t < F2_OFF) {
    int i = t / F1_J, r = t % F1_J;
    int blk = r >> 9, q = r & 511;
    int ln = q >> 3, e = q & 7;
    int nt = blk / 3, s = blk - nt*3;
    int n  = nt*16 + (ln & 15);
    int kp = s*32 + (ln >> 4)*8 + e;                 // x layout: [0..12]bt [13..15]0 [16..79]feat [80..95]0
    if (n < 77) {
      if (kp < 13)                  v = W1[i*5929 + kp*77 + n];
      else if (kp >= 16 && kp < 80) v = W1[i*5929 + (kp-3)*77 + n];
    }
  } else if (t < FP_OFF) {
    int u = t - F2_OFF;
    int i = u / F2_J, r = u % F2_J;
    int blk = r >> 9, q = r & 511;
    int ln = q >> 3, e = q & 7;
    int nt = blk / 3, s = blk - nt*3;
    int n  = nt*16 + (ln & 15);
    int k  = s*32 + (ln >> 4)*8 + e;
    if (k < 77) v = W2[i*4928 + k*64 + n];
  } else {
    int u = t - FP_OFF;
    int blk = u >> 9, q = u & 511;
    int ln = q >> 3, e = q & 7;
    int nt = blk / 9, s = blk - nt*9;
    int n  = nt*16 + (ln & 15);
    int k  = s*32 + (ln >> 4)*8 + e;                 // k < 288 always
    v = Wp[k*64 + n];
  }
  img[t] = f2bf(v);
}

// bone transforms for joint jj into btL (stride 24): cols 0..8 pose, 9..11 rel, 12=|rel|
__device__ __forceinline__ void stage_bt(short* btL, const float* __restrict__ pose,
                                         const float* __restrict__ rel,
                                         int rb, int jj, int tid) {
#pragma unroll 1
  for (int t = tid; t < 1024; t += 512) {
    int r = t >> 4, cc = t & 15;
    size_t pb = (size_t)(rb + r)*216 + (size_t)jj*9;
    size_t rl = (size_t)(rb + r)*72  + (size_t)jj*3;
    if (cc < 9)       btL[r*24 + cc] = sbf(pose[pb + cc]);
    else if (cc < 12) btL[r*24 + cc] = sbf(rel[rl + (cc-9)]);
    else if (cc == 12) {
      float x0 = rel[rl], x1 = rel[rl+1], x2 = rel[rl+2];
      btL[r*24 + 12] = sbf(sqrtf(x0*x0 + x1*x1 + x2*x2));
    }
  }
}

// 64 rows/WG, 8 waves = 4 m-tiles x 2 n-halves. Weights direct L2->VGPR.
__global__ __launch_bounds__(512, 6) void enc_kernel(
    const float* __restrict__ pose, const float* __restrict__ rel,
    const float* __restrict__ bp,  const float* __restrict__ b1,
    const float* __restrict__ b2,  const short* __restrict__ img,
    float* __restrict__ out) {
  // one LDS pool, manual carve (root scratch overlays featL+hL)
  __shared__ __align__(16) short lds[25608];        // 51,216 B -> 3 WG/CU
  short* featL = lds;                               // 4 slots x [64][72]
  short* hL    = lds + 18432;                       // [64][88]
  short* btL   = lds + 24064;                       // [64][24]
  short* zp    = lds + 25600;                       // 16B of zeros (broadcast reads)

  const int tid  = threadIdx.x;
  const int lane = tid & 63;
  const int wid  = tid >> 6;
  const int mt   = wid & 3;
  const int nh   = wid >> 2;
  const int rm   = lane & 15;
  const int g    = lane >> 4;
  const int rb   = blockIdx.x * 64;
  const int row  = mt*16 + rm;

  // ---- prologue: zeros + root scratch (stride 296 over lds[0..18944)) + bt[0] ----
  if (tid < 8) zp[tid] = 0;
  { int r = tid >> 2, c = tid & 3;
    if (c < 3) btL[r*24 + 13 + c] = 0; }            // bt pad cols 13..15 (tid<256 covers r<64)
  {
    int r = tid >> 3, j0 = (tid & 7) * 3;
    const float* pr = pose + (size_t)(rb + r)*216;
    const float* rr = rel  + (size_t)(rb + r)*72;
    short* dst = lds + r*296;
#pragma unroll
    for (int dj = 0; dj < 3; ++dj) {
      int jj = j0 + dj;
#pragma unroll
      for (int w = 0; w < 9; ++w) dst[jj*12 + w]     = sbf(pr[jj*9 + w]);
#pragma unroll
      for (int w = 0; w < 3; ++w) dst[jj*12 + 9 + w] = sbf(rr[jj*3 + w]);
    }
  }
  stage_bt(btL, pose, rel, rb, 0, tid);
  BAR();

  // ---- root: bonefeat(64x288) @ Wp + bp -> feat slot 3 ----
  f32x4 racc0 = {0.f,0.f,0.f,0.f}, racc1 = {0.f,0.f,0.f,0.f};
  {
    const short8* fp0 = (const short8*)(img + FP_OFF) + (size_t)(nh*2*9)*64 + lane;
    const short8* fp1 = fp0 + 9*64;
#pragma unroll
    for (int s = 0; s < 9; ++s) {
      short8 a = *(const short8*)(lds + row*296 + s*32 + g*8);
      racc0 = MFMA(a, fp0[s*64], racc0);
      racc1 = MFMA(a, fp1[s*64], racc1);
    }
  }
  BAR();                                            // all scratch reads done
  {
    int n0 = nh*32 + rm, n1 = n0 + 16;
    float p0 = bp[n0], p1 = bp[n1];
#pragma unroll
    for (int r4 = 0; r4 < 4; ++r4) {
      int rr2 = mt*16 + g*4 + r4;
      featL[3*4608 + rr2*72 + n0] = sbf(racc0[r4] + p0);
      featL[3*4608 + rr2*72 + n1] = sbf(racc1[r4] + p1);
    }
  }
  BAR();

  // slot schedule (liveness-verified over PARENTS), 2-bit packed
  const unsigned long long PS_PACK = 0x4E4E15393903ULL;
  const unsigned long long SS_PACK = 0x04E43804E4E4ULL;
  const unsigned LEAF = 0x00C08C00u;                // 10,11,15,22,23

  float* outr = out + (size_t)(rb + mt*16 + g*4)*1536;

#pragma unroll 1
  for (int i = 0; i < NJ; ++i) {
    // ---- GEMM1: h = relu(x @ W1 + b1), K'=96 ----
    const int ps = (int)((PS_PACK >> (2*i)) & 3ull);
    const short* fb  = featL + ps*4608 + row*72;
    const short* a0p = (g < 2) ? (const short*)(btL + row*24 + g*8) : (fb + (g-2)*8);
    const short* a2p = (g < 2) ? (fb + 48 + g*8) : (const short*)zp;
    short8 a0 = *(const short8*)a0p;                // k' 0..31
    short8 a1 = *(const short8*)(fb + 16 + g*8);    // k' 32..63
    short8 a2 = *(const short8*)a2p;                // k' 64..95 (g>=2: zeros)
    const short8* f1 = (const short8*)(img + (size_t)i*F1_J) + lane;
    const float* b1i = b1 + i*77;
    const int hrow = (mt*16 + g*4)*88;
#define G1_TILE(NT) { \
      const short8* wp_ = f1 + (NT)*192; \
      f32x4 acc = {0.f,0.f,0.f,0.f}; \
      acc = MFMA(a0, wp_[0],   acc); \
      acc = MFMA(a1, wp_[64],  acc); \
      acc = MFMA(a2, wp_[128], acc); \
      const int n = (NT)*16 + rm; \
      const float bias = (n < 77) ? b1i[n] : 0.f; \
      _Pragma("unroll") \
      for (int r4 = 0; r4 < 4; ++r4) \
        hL[hrow + r4*88 + n] = sbf(fmaxf(acc[r4] + bias, 0.f)); \
    }
    if (nh == 0) { G1_TILE(0); G1_TILE(1); G1_TILE(2); }
    else         { G1_TILE(3); G1_TILE(4); }
#undef G1_TILE
    BAR();                                          // h visible; btL reads done

    // ---- GEMM2: f = relu(h @ W2 + b2), K=96 ----
    const short* hb  = hL + row*88;
    const short* h2p = (g < 2) ? (hb + 64 + g*8) : (const short*)zp;
    short8 h0 = *(const short8*)(hb + g*8);
    short8 h1 = *(const short8*)(hb + 32 + g*8);
    short8 h2 = *(const short8*)h2p;
    const int ss = ((LEAF >> i) & 1u) ? -1 : (int)((SS_PACK >> (2*i)) & 3ull);
    const short8* f2 = (const short8*)(img + F2_OFF + (size_t)i*F2_J) + lane;
    const float* b2i = b2 + i*64;
#define G2_TILE(Q) { \
      const int nt = nh*2 + (Q); \
      const short8* wp_ = f2 + nt*192; \
      f32x4 acc = {0.f,0.f,0.f,0.f}; \
      acc = MFMA(h0, wp_[0],   acc); \
      acc = MFMA(h1, wp_[64],  acc); \
      acc = MFMA(h2, wp_[128], acc); \
      const int n = nt*16 + rm; \
      const float bias = b2i[n]; \
      _Pragma("unroll") \
      for (int r4 = 0; r4 < 4; ++r4) { \
        float v = fmaxf(acc[r4] + bias, 0.f); \
        outr[(size_t)r4*1536 + i*64 + n] = v; \
        if (ss >= 0) featL[ss*4608 + (mt*16 + g*4 + r4)*72 + n] = sbf(v); \
      } \
    }
    G2_TILE(0); G2_TILE(1);
#undef G2_TILE

    if (i < NJ-1) stage_bt(btL, pose, rel, rb, i+1, tid);  // overlaps epilogue
    BAR();                                          // featL/btL visible
  }
}

extern "C" void kernel_launch(void* const* d_in, const int* in_sizes, int n_in,
                              void* d_out, int out_size, void* d_ws, size_t ws_size,
                              hipStream_t stream) {
  const float* pose = (const float*)d_in[0];
  const float* rel  = (const float*)d_in[1];
  const float* Wp   = (const float*)d_in[2];
  const float* bp   = (const float*)d_in[3];
  const float* W1   = (const float*)d_in[4];
  const float* b1   = (const float*)d_in[5];
  const float* W2   = (const float*)d_in[6];
  const float* b2   = (const float*)d_in[7];
  float* outp = (float*)d_out;
  short* img  = (short*)d_ws;            // 700,416 B scratch
  const int Bn = in_sizes[0] / 216;
  prep_kernel<<<(IMG_SHORTS + 255)/256, 256, 0, stream>>>(W1, W2, Wp, img);
  enc_kernel<<<Bn/64, 512, 0, stream>>>(pose, rel, bp, b1, b2, img, outp);
}

// Round 5
// 231.733 us; speedup vs baseline: 1.1720x; 1.1720x over previous
//
#include <hip/hip_runtime.h>
#include <hip/hip_bf16.h>
#include <math.h>

typedef __attribute__((ext_vector_type(8))) short short8;
typedef __attribute__((ext_vector_type(4))) short bt4;
typedef __attribute__((ext_vector_type(4))) float f32x4;

#define NJ 24

// ---- ws image: per-fragment 1KB blocks (64 lanes x 16B), lane-major ----
// GEMM1: per joint 15 blocks (blk=nt*3+s)  lane(rm,g): W1T[n=nt*16+rm][k'=s*32+g*8..+7]
// GEMM2: per joint 12 blocks (blk=nt*3+s)  W2T[n][k]
// Wp   : 36 blocks (blk=nt*9+s)            WpT[n][k']  k' in [pose216|rel72] order!
#define F1_J   7680
#define F2_OFF (NJ*F1_J)
#define F2_J   6144
#define FP_OFF (F2_OFF + NJ*F2_J)
#define IMG_SHORTS (FP_OFF + 36*512)        // 350208 shorts = 700416 B

#define MFMA(A,B,C) __builtin_amdgcn_mfma_f32_16x16x32_bf16((A),(B),(C),0,0,0)

// DFS topological order over PARENTS + 3-slot liveness schedule (re-verified by
// simulation: parent slot always holds parent's feat at read time; overwrites
// only after all children consumed; in-iteration read precedes write)
__constant__ int ORD[24] = {0,1,4,7,10, 2,5,8,11, 3,6,9, 12,15, 13,16,18,20,22, 14,17,19,21,23};
__constant__ int PSL[24] = {2,0,1,1,1,  0,1,1,1,  0,0,0,  0,1,   0,1,1,1,1,    0,0,0,0,0};
__constant__ int SSL[24] = {0,1,1,1,-1, 1,1,1,-1, 0,0,0,  1,-1,  1,1,1,1,-1,   0,0,0,0,-1};

__device__ __forceinline__ short f2bf(float f) {      // prep only
  union { float f; unsigned u; } v; v.f = f;
  unsigned r = v.u + 0x7FFFu + ((v.u >> 16) & 1u);    // RNE
  return (short)(r >> 16);
}
__device__ __forceinline__ short sbf(float f) {
  __hip_bfloat16 h = __float2bfloat16(f);
  return *reinterpret_cast<short*>(&h);
}
// pack 8 f32 -> short8 bf16 (RNE) via v_cvt_pk_bf16_f32
__device__ __forceinline__ short8 pk8(f32x4 lo, f32x4 hi) {
  union { short8 s; unsigned u[4]; } r;
  asm("v_cvt_pk_bf16_f32 %0, %1, %2" : "=v"(r.u[0]) : "v"(lo[0]), "v"(lo[1]));
  asm("v_cvt_pk_bf16_f32 %0, %1, %2" : "=v"(r.u[1]) : "v"(lo[2]), "v"(lo[3]));
  asm("v_cvt_pk_bf16_f32 %0, %1, %2" : "=v"(r.u[2]) : "v"(hi[0]), "v"(hi[1]));
  asm("v_cvt_pk_bf16_f32 %0, %1, %2" : "=v"(r.u[3]) : "v"(hi[2]), "v"(hi[3]));
  return r.s;
}

__global__ __launch_bounds__(256) void prep_kernel(
    const float* __restrict__ W1, const float* __restrict__ W2,
    const float* __restrict__ Wp, short* __restrict__ img) {
  int t = blockIdx.x * 256 + threadIdx.x;
  if (t >= IMG_SHORTS) return;
  float v = 0.f;
  if (t < F2_OFF) {
    int i = t / F1_J, r = t % F1_J;
    int blk = r >> 9, q = r & 511;
    int ln = q >> 3, e = q & 7;
    int nt = blk / 3, s = blk - nt*3;
    int n  = nt*16 + (ln & 15);
    int kp = s*32 + (ln >> 4)*8 + e;                 // x: [0..12]bt [13..15]0 [16..79]feat [80..95]0
    if (n < 77) {
      if (kp < 13)                  v = W1[i*5929 + kp*77 + n];
      else if (kp >= 16 && kp < 80) v = W1[i*5929 + (kp-3)*77 + n];
    }
  } else if (t < FP_OFF) {
    int u = t - F2_OFF;
    int i = u / F2_J, r = u % F2_J;
    int blk = r >> 9, q = r & 511;
    int ln = q >> 3, e = q & 7;
    int nt = blk / 3, s = blk - nt*3;
    int n  = nt*16 + (ln & 15);
    int k  = s*32 + (ln >> 4)*8 + e;
    if (k < 77) v = W2[i*4928 + k*64 + n];
  } else {
    // WpT rows permuted to the A-side's [pose 216 | rel 72] direct-load order:
    // reference row index = j*12 + w  (bone_features is per-joint [9 pose | 3 rel])
    int u = t - FP_OFF;
    int blk = u >> 9, q = u & 511;
    int ln = q >> 3, e = q & 7;
    int nt = blk / 9, s = blk - nt*9;
    int n  = nt*16 + (ln & 15);
    int kp = s*32 + (ln >> 4)*8 + e;                 // k' < 288, A-load order
    int j, w;
    if (kp < 216) { j = kp / 9;       w = kp % 9; }
    else          { j = (kp-216) / 3; w = 9 + (kp-216) % 3; }
    v = Wp[(j*12 + w)*64 + n];
  }
  img[t] = f2bf(v);
}

struct BT { float t0, t1, t2, t3; };
__device__ __forceinline__ BT bt_load(const float* __restrict__ pose,
                                      const float* __restrict__ rel,
                                      int rw0, int jj, int lane) {
  int r = lane >> 2, q = lane & 3;
  const float* pb = pose + (size_t)(rw0 + r)*216 + (size_t)jj*9;
  const float* rb = rel  + (size_t)(rw0 + r)*72  + (size_t)jj*3;
  BT b;
  if (q == 0)      { b.t0 = pb[0]; b.t1 = pb[1]; b.t2 = pb[2]; b.t3 = pb[3]; }
  else if (q == 1) { b.t0 = pb[4]; b.t1 = pb[5]; b.t2 = pb[6]; b.t3 = pb[7]; }
  else             { b.t0 = pb[8]; b.t1 = rb[0]; b.t2 = rb[1]; b.t3 = rb[2]; }
  return b;
}
__device__ __forceinline__ void bt_write(short* btL, BT b, int lane) {
  int r = lane >> 2, q = lane & 3;
  bt4 bw;
  if (q == 3) {
    float nv = sqrtf(b.t1*b.t1 + b.t2*b.t2 + b.t3*b.t3);
    bw[0] = sbf(nv); bw[1] = 0; bw[2] = 0; bw[3] = 0;
  } else {
    bw[0] = sbf(b.t0); bw[1] = sbf(b.t1); bw[2] = sbf(b.t2); bw[3] = sbf(b.t3);
  }
  *(bt4*)(btL + r*24 + q*4) = bw;
}

// 256 threads = 4 waves; each wave owns 16 rows + the whole tree. ZERO barriers.
// Per-wave LDS slice: feat 3x[16][72] | h [16][80] | bt [16][24]  = 10,240 B
__global__ __launch_bounds__(256, 4) void enc_kernel(
    const float* __restrict__ pose, const float* __restrict__ rel,
    const float* __restrict__ bp,  const float* __restrict__ b1,
    const float* __restrict__ b2,  const short* __restrict__ img,
    float* __restrict__ out) {
  __shared__ __align__(16) short lds[4*5120];        // 40,960 B -> 4 WG/CU exact

  const int tid  = threadIdx.x;
  const int lane = tid & 63;
  const int wv   = tid >> 6;
  short* myl   = lds + wv*5120;
  short* featL = myl;                                // 3 slots x 1152 shorts
  short* hL    = myl + 3456;                         // [16][80]
  short* btL   = myl + 4736;                         // [16][24]

  const int cl  = lane & 15;                         // A m-row / C n-col
  const int g   = lane >> 4;                         // k-octet / C row-group
  const int rw0 = blockIdx.x*64 + wv*16;             // wave's first batch row

  const short8 zz = {0,0,0,0,0,0,0,0};

  // bt loads for joint ORD[0]=0 issued first (written after root)
  BT nb = bt_load(pose, rel, rw0, 0, lane);

  // ---- root: bonefeat(16x288) @ Wp + bp -> feat slot 2 ----
  f32x4 racc[4] = {{0,0,0,0},{0,0,0,0},{0,0,0,0},{0,0,0,0}};
  {
    const float* pr = pose + (size_t)(rw0 + cl)*216;
    const float* rr = rel  + (size_t)(rw0 + cl)*72;
    const short8* fp = (const short8*)(img + FP_OFF) + lane;
#pragma unroll
    for (int s = 0; s < 9; ++s) {
      int k0 = s*32 + g*8;
      const float* src = (k0 < 216) ? (pr + k0) : (rr + (k0 - 216));
      f32x4 lo = *(const f32x4*)(src);
      f32x4 hi = *(const f32x4*)(src + 4);
      short8 a = pk8(lo, hi);
#pragma unroll
      for (int nt = 0; nt < 4; ++nt)
        racc[nt] = MFMA(a, fp[(nt*9 + s)*64], racc[nt]);
    }
  }
#pragma unroll
  for (int nt = 0; nt < 4; ++nt) {
    int n = nt*16 + cl;
    float bias = bp[n];
#pragma unroll
    for (int r4 = 0; r4 < 4; ++r4)
      featL[2*1152 + (g*4 + r4)*72 + n] = sbf(racc[nt][r4] + bias);
  }
  bt_write(btL, nb, lane);

  // ---- main DFS loop, zero barriers ----
#pragma unroll 1
  for (int p = 0; p < NJ; ++p) {
    const int j  = ORD[p];
    const int ps = PSL[p];
    const int ss = SSL[p];

    // A1 fragments (x = [bt13|pad|feat64|pad])
    const short* fb = featL + ps*1152 + cl*72;
    short8 a0 = (g < 2) ? *(const short8*)(btL + cl*24 + g*8)
                        : *(const short8*)(fb + (g-2)*8);
    short8 a1 = *(const short8*)(fb + 16 + g*8);
    short8 a2 = (g < 2) ? *(const short8*)(fb + 48 + g*8) : zz;

    if (p < NJ-1) nb = bt_load(pose, rel, rw0, ORD[p+1], lane);  // early issue

    // GEMM1: 5 n-tiles x K'=96
    const short8* f1 = (const short8*)(img + (size_t)j*F1_J) + lane;
    f32x4 acc1[5] = {{0,0,0,0},{0,0,0,0},{0,0,0,0},{0,0,0,0},{0,0,0,0}};
#pragma unroll
    for (int nt = 0; nt < 5; ++nt) {
      acc1[nt] = MFMA(a0, f1[(nt*3+0)*64], acc1[nt]);
      acc1[nt] = MFMA(a1, f1[(nt*3+1)*64], acc1[nt]);
      acc1[nt] = MFMA(a2, f1[(nt*3+2)*64], acc1[nt]);
    }
    // h epilogue -> LDS (wave-private; in-wave DS ordering + compiler lgkmcnt)
    const float* b1i = b1 + j*77;
#pragma unroll
    for (int nt = 0; nt < 5; ++nt) {
      int n = nt*16 + cl;
      float bias = (n < 77) ? b1i[n] : 0.f;
#pragma unroll
      for (int r4 = 0; r4 < 4; ++r4)
        hL[(g*4 + r4)*80 + n] = sbf(fmaxf(acc1[nt][r4] + bias, 0.f));
    }
    // GEMM2 fragments
    short8 h0 = *(const short8*)(hL + cl*80 + g*8);
    short8 h1 = *(const short8*)(hL + cl*80 + 32 + g*8);
    short8 h2 = (g < 2) ? *(const short8*)(hL + cl*80 + 64 + g*8) : zz;
    const short8* f2p = (const short8*)(img + F2_OFF + (size_t)j*F2_J) + lane;
    f32x4 acc2[4] = {{0,0,0,0},{0,0,0,0},{0,0,0,0},{0,0,0,0}};
#pragma unroll
    for (int nt = 0; nt < 4; ++nt) {
      acc2[nt] = MFMA(h0, f2p[(nt*3+0)*64], acc2[nt]);
      acc2[nt] = MFMA(h1, f2p[(nt*3+1)*64], acc2[nt]);
      acc2[nt] = MFMA(h2, f2p[(nt*3+2)*64], acc2[nt]);
    }
    if (p < NJ-1) bt_write(btL, nb, lane);           // late write (T14 split)

    // out + feat epilogue
    const float* b2i = b2 + j*64;
    float* outb = out + (size_t)(rw0 + g*4)*1536 + j*64;
#pragma unroll
    for (int nt = 0; nt < 4; ++nt) {
      int n = nt*16 + cl;
      float bias = b2i[n];
#pragma unroll
      for (int r4 = 0; r4 < 4; ++r4) {
        float v = fmaxf(acc2[nt][r4] + bias, 0.f);
        outb[(size_t)r4*1536 + n] = v;
        if (ss >= 0) featL[ss*1152 + (g*4 + r4)*72 + n] = sbf(v);
      }
    }
  }
}

extern "C" void kernel_launch(void* const* d_in, const int* in_sizes, int n_in,
                              void* d_out, int out_size, void* d_ws, size_t ws_size,
                              hipStream_t stream) {
  const float* pose = (const float*)d_in[0];
  const float* rel  = (const float*)d_in[1];
  const float* Wp   = (const float*)d_in[2];
  const float* bp   = (const float*)d_in[3];
  const float* W1   = (const float*)d_in[4];
  const float* b1   = (const float*)d_in[5];
  const float* W2   = (const float*)d_in[6];
  const float* b2   = (const float*)d_in[7];
  float* outp = (float*)d_out;
  short* img  = (short*)d_ws;            // 700,416 B scratch
  const int Bn = in_sizes[0] / 216;
  prep_kernel<<<(IMG_SHORTS + 255)/256, 256, 0, stream>>>(W1, W2, Wp, img);
  enc_kernel<<<Bn/64, 256, 0, stream>>>(pose, rel, bp, b1, b2, img, outp);
}

// Round 6
// 201.405 us; speedup vs baseline: 1.3485x; 1.1506x over previous
//
#include <hip/hip_runtime.h>
#include <hip/hip_bf16.h>
#include <math.h>

typedef __attribute__((ext_vector_type(8))) short short8;
typedef __attribute__((ext_vector_type(4))) short bt4;
typedef __attribute__((ext_vector_type(4))) float f32x4;

#define NJ 24

// ---- ws image: per-fragment 1KB blocks (64 lanes x 16B), lane-major ----
// GEMM1: per joint 15 blocks (blk=nt*3+s)  lane(rm,g): W1T[n=nt*16+rm][k'=s*32+g*8..+7]
// GEMM2: per joint 12 blocks (blk=nt*3+s)  W2T[n][k]
// Wp   : 36 blocks (blk=nt*9+s)            WpT[n][k']  k' in [pose216|rel72] order
#define F1_J   7680
#define F2_OFF (NJ*F1_J)
#define F2_J   6144
#define FP_OFF (F2_OFF + NJ*F2_J)
#define IMG_SHORTS (FP_OFF + 36*512)        // 350208 shorts = 700416 B

#define MFMA(A,B,C) __builtin_amdgcn_mfma_f32_16x16x32_bf16((A),(B),(C),0,0,0)

// DFS topological order over PARENTS + 3-slot liveness schedule (verified)
__constant__ int ORD[24] = {0,1,4,7,10, 2,5,8,11, 3,6,9, 12,15, 13,16,18,20,22, 14,17,19,21,23};
__constant__ int PSL[24] = {2,0,1,1,1,  0,1,1,1,  0,0,0,  0,1,   0,1,1,1,1,    0,0,0,0,0};
__constant__ int SSL[24] = {0,1,1,1,-1, 1,1,1,-1, 0,0,0,  1,-1,  1,1,1,1,-1,   0,0,0,0,-1};

__device__ __forceinline__ short f2bf(float f) {      // prep only
  union { float f; unsigned u; } v; v.f = f;
  unsigned r = v.u + 0x7FFFu + ((v.u >> 16) & 1u);    // RNE
  return (short)(r >> 16);
}
__device__ __forceinline__ short sbf(float f) {
  __hip_bfloat16 h = __float2bfloat16(f);
  return *reinterpret_cast<short*>(&h);
}
// pack 8 f32 -> short8 bf16 (RNE) via v_cvt_pk_bf16_f32
__device__ __forceinline__ short8 pk8(f32x4 lo, f32x4 hi) {
  union { short8 s; unsigned u[4]; } r;
  asm("v_cvt_pk_bf16_f32 %0, %1, %2" : "=v"(r.u[0]) : "v"(lo[0]), "v"(lo[1]));
  asm("v_cvt_pk_bf16_f32 %0, %1, %2" : "=v"(r.u[1]) : "v"(lo[2]), "v"(lo[3]));
  asm("v_cvt_pk_bf16_f32 %0, %1, %2" : "=v"(r.u[2]) : "v"(hi[0]), "v"(hi[1]));
  asm("v_cvt_pk_bf16_f32 %0, %1, %2" : "=v"(r.u[3]) : "v"(hi[2]), "v"(hi[3]));
  return r.s;
}

__global__ __launch_bounds__(256) void prep_kernel(
    const float* __restrict__ W1, const float* __restrict__ W2,
    const float* __restrict__ Wp, short* __restrict__ img) {
  int t = blockIdx.x * 256 + threadIdx.x;
  if (t >= IMG_SHORTS) return;
  float v = 0.f;
  if (t < F2_OFF) {
    int i = t / F1_J, r = t % F1_J;
    int blk = r >> 9, q = r & 511;
    int ln = q >> 3, e = q & 7;
    int nt = blk / 3, s = blk - nt*3;
    int n  = nt*16 + (ln & 15);
    int kp = s*32 + (ln >> 4)*8 + e;                 // x: [0..12]bt [13..15]0 [16..79]feat [80..95]0
    if (n < 77) {
      if (kp < 13)                  v = W1[i*5929 + kp*77 + n];
      else if (kp >= 16 && kp < 80) v = W1[i*5929 + (kp-3)*77 + n];
    }
  } else if (t < FP_OFF) {
    int u = t - F2_OFF;
    int i = u / F2_J, r = u % F2_J;
    int blk = r >> 9, q = r & 511;
    int ln = q >> 3, e = q & 7;
    int nt = blk / 3, s = blk - nt*3;
    int n  = nt*16 + (ln & 15);
    int k  = s*32 + (ln >> 4)*8 + e;
    if (k < 77) v = W2[i*4928 + k*64 + n];
  } else {
    // WpT rows permuted to the A-side's [pose 216 | rel 72] direct-load order
    int u = t - FP_OFF;
    int blk = u >> 9, q = u & 511;
    int ln = q >> 3, e = q & 7;
    int nt = blk / 9, s = blk - nt*9;
    int n  = nt*16 + (ln & 15);
    int kp = s*32 + (ln >> 4)*8 + e;                 // k' < 288, A-load order
    int j, w;
    if (kp < 216) { j = kp / 9;       w = kp % 9; }
    else          { j = (kp-216) / 3; w = 9 + (kp-216) % 3; }
    v = Wp[(j*12 + w)*64 + n];
  }
  img[t] = f2bf(v);
}

struct BT { float t0, t1, t2, t3; };
__device__ __forceinline__ BT bt_load(const float* __restrict__ pose,
                                      const float* __restrict__ rel,
                                      int rw0, int jj, int lane) {
  int r = lane >> 2, q = lane & 3;
  const float* pb = pose + (size_t)(rw0 + r)*216 + (size_t)jj*9;
  const float* rb = rel  + (size_t)(rw0 + r)*72  + (size_t)jj*3;
  BT b;
  if (q == 0)      { b.t0 = pb[0]; b.t1 = pb[1]; b.t2 = pb[2]; b.t3 = pb[3]; }
  else if (q == 1) { b.t0 = pb[4]; b.t1 = pb[5]; b.t2 = pb[6]; b.t3 = pb[7]; }
  else             { b.t0 = pb[8]; b.t1 = rb[0]; b.t2 = rb[1]; b.t3 = rb[2]; }
  return b;
}
__device__ __forceinline__ void bt_write(short* btL, BT b, int lane) {
  int r = lane >> 2, q = lane & 3;
  bt4 bw;
  if (q == 3) {
    float nv = sqrtf(b.t1*b.t1 + b.t2*b.t2 + b.t3*b.t3);
    bw[0] = sbf(nv); bw[1] = 0; bw[2] = 0; bw[3] = 0;
  } else {
    bw[0] = sbf(b.t0); bw[1] = sbf(b.t1); bw[2] = sbf(b.t2); bw[3] = sbf(b.t3);
  }
  *(bt4*)(btL + r*24 + q*4) = bw;
}

// 256 threads = 4 waves; each wave owns 16 rows + the whole tree. ZERO barriers.
// Weights held in named VGPR fragment arrays, loaded one GEMM-phase ahead so
// 12-27 global loads stay in flight (breaks the R5 load-serialization stall).
__global__ __launch_bounds__(256, 2) void enc_kernel(
    const float* __restrict__ pose, const float* __restrict__ rel,
    const float* __restrict__ bp,  const float* __restrict__ b1,
    const float* __restrict__ b2,  const short* __restrict__ img,
    float* __restrict__ out) {
  __shared__ __align__(16) short lds[4*5120];        // 40,960 B

  const int tid  = threadIdx.x;
  const int lane = tid & 63;
  const int wv   = tid >> 6;
  short* myl   = lds + wv*5120;
  short* featL = myl;                                // 3 slots x 1152 shorts
  short* hL    = myl + 3456;                         // [16][80]
  short* btL   = myl + 4736;                         // [16][24]

  const int cl  = lane & 15;                         // A m-row / C n-col
  const int g   = lane >> 4;                         // k-octet / C row-group
  const int rw0 = blockIdx.x*64 + wv*16;             // wave's first batch row

  const short8 zz = {0,0,0,0,0,0,0,0};

  const short8* f1g = (const short8*)img + lane;
  const short8* f2g = (const short8*)(img + F2_OFF) + lane;
  const short8* fpg = (const short8*)(img + FP_OFF) + lane;

  // bt loads for joint ORD[0]=0 issued first (written after root)
  BT nb = bt_load(pose, rel, rw0, 0, lane);

  // W1[joint 0] prefetch — in flight across the entire root phase
  short8 fw1[15];
#pragma unroll
  for (int b = 0; b < 15; ++b) fw1[b] = f1g[b*64];

  // ---- root: bonefeat(16x288) @ Wp + bp -> feat slot 2 ----
  f32x4 racc[4] = {{0,0,0,0},{0,0,0,0},{0,0,0,0},{0,0,0,0}};
  {
    const float* pr = pose + (size_t)(rw0 + cl)*216;
    const float* rr = rel  + (size_t)(rw0 + cl)*72;
    short8 av[9];
#pragma unroll
    for (int s = 0; s < 9; ++s) {                    // 18 input loads in flight
      int k0 = s*32 + g*8;
      const float* src = (k0 < 216) ? (pr + k0) : (rr + (k0 - 216));
      f32x4 lo = *(const f32x4*)(src);
      f32x4 hi = *(const f32x4*)(src + 4);
      av[s] = pk8(lo, hi);
    }
#pragma unroll
    for (int nt = 0; nt < 4; ++nt) {
      short8 fwp[9];
#pragma unroll
      for (int s = 0; s < 9; ++s) fwp[s] = fpg[(nt*9 + s)*64];   // 9 in flight
#pragma unroll
      for (int s = 0; s < 9; ++s) racc[nt] = MFMA(av[s], fwp[s], racc[nt]);
    }
  }
#pragma unroll
  for (int nt = 0; nt < 4; ++nt) {
    int n = nt*16 + cl;
    float bias = bp[n];
#pragma unroll
    for (int r4 = 0; r4 < 4; ++r4)
      featL[2*1152 + (g*4 + r4)*72 + n] = sbf(racc[nt][r4] + bias);
  }
  bt_write(btL, nb, lane);

  // ---- main DFS loop, zero barriers ----
#pragma unroll 1
  for (int p = 0; p < NJ; ++p) {
    const int j  = ORD[p];
    const int ps = PSL[p];
    const int ss = SSL[p];

    // W2[j] issued now; consumed after GEMM1 (one full phase of flight time)
    short8 fw2[12];
#pragma unroll
    for (int b = 0; b < 12; ++b) fw2[b] = f2g[(size_t)j*768 + b*64];

    // A1 fragments (x = [bt13|pad|feat64|pad])
    const short* fb = featL + ps*1152 + cl*72;
    short8 a0 = (g < 2) ? *(const short8*)(btL + cl*24 + g*8)
                        : *(const short8*)(fb + (g-2)*8);
    short8 a1 = *(const short8*)(fb + 16 + g*8);
    short8 a2 = (g < 2) ? *(const short8*)(fb + 48 + g*8) : zz;

    if (p < NJ-1) nb = bt_load(pose, rel, rw0, ORD[p+1], lane);  // early issue

    // GEMM1: 5 n-tiles x K'=96 (weights already resident in fw1)
    f32x4 acc1[5] = {{0,0,0,0},{0,0,0,0},{0,0,0,0},{0,0,0,0},{0,0,0,0}};
#pragma unroll
    for (int nt = 0; nt < 5; ++nt) {
      acc1[nt] = MFMA(a0, fw1[nt*3+0], acc1[nt]);
      acc1[nt] = MFMA(a1, fw1[nt*3+1], acc1[nt]);
      acc1[nt] = MFMA(a2, fw1[nt*3+2], acc1[nt]);
    }
    // h epilogue -> LDS (wave-private)
    const float* b1i = b1 + j*77;
#pragma unroll
    for (int nt = 0; nt < 5; ++nt) {
      int n = nt*16 + cl;
      float bias = (n < 77) ? b1i[n] : 0.f;
#pragma unroll
      for (int r4 = 0; r4 < 4; ++r4)
        hL[(g*4 + r4)*80 + n] = sbf(fmaxf(acc1[nt][r4] + bias, 0.f));
    }
    // W1[next joint] issued now; consumed at next iteration's GEMM1
    if (p < NJ-1) {
      const int jn = ORD[p+1];
#pragma unroll
      for (int b = 0; b < 15; ++b) fw1[b] = f1g[(size_t)jn*960 + b*64];
    }
    // GEMM2 fragments (compiler inserts lgkmcnt for the RAW)
    short8 h0 = *(const short8*)(hL + cl*80 + g*8);
    short8 h1 = *(const short8*)(hL + cl*80 + 32 + g*8);
    short8 h2 = (g < 2) ? *(const short8*)(hL + cl*80 + 64 + g*8) : zz;
    f32x4 acc2[4] = {{0,0,0,0},{0,0,0,0},{0,0,0,0},{0,0,0,0}};
#pragma unroll
    for (int nt = 0; nt < 4; ++nt) {
      acc2[nt] = MFMA(h0, fw2[nt*3+0], acc2[nt]);
      acc2[nt] = MFMA(h1, fw2[nt*3+1], acc2[nt]);
      acc2[nt] = MFMA(h2, fw2[nt*3+2], acc2[nt]);
    }
    if (p < NJ-1) bt_write(btL, nb, lane);           // late write (T14 split)

    // out + feat epilogue
    const float* b2i = b2 + j*64;
    float* outb = out + (size_t)(rw0 + g*4)*1536 + j*64;
#pragma unroll
    for (int nt = 0; nt < 4; ++nt) {
      int n = nt*16 + cl;
      float bias = b2i[n];
#pragma unroll
      for (int r4 = 0; r4 < 4; ++r4) {
        float v = fmaxf(acc2[nt][r4] + bias, 0.f);
        outb[(size_t)r4*1536 + n] = v;
        if (ss >= 0) featL[ss*1152 + (g*4 + r4)*72 + n] = sbf(v);
      }
    }
  }
}

extern "C" void kernel_launch(void* const* d_in, const int* in_sizes, int n_in,
                              void* d_out, int out_size, void* d_ws, size_t ws_size,
                              hipStream_t stream) {
  const float* pose = (const float*)d_in[0];
  const float* rel  = (const float*)d_in[1];
  const float* Wp   = (const float*)d_in[2];
  const float* bp   = (const float*)d_in[3];
  const float* W1   = (const float*)d_in[4];
  const float* b1   = (const float*)d_in[5];
  const float* W2   = (const float*)d_in[6];
  const float* b2   = (const float*)d_in[7];
  float* outp = (float*)d_out;
  short* img  = (short*)d_ws;            // 700,416 B scratch
  const int Bn = in_sizes[0] / 216;
  prep_kernel<<<(IMG_SHORTS + 255)/256, 256, 0, stream>>>(W1, W2, Wp, img);
  enc_kernel<<<Bn/64, 256, 0, stream>>>(pose, rel, bp, b1, b2, img, outp);
}